// Round 6
// baseline (90.628 us; speedup 1.0000x reference)
//
#include <hip/hip_runtime.h>

// DWT (Haar) forward: x (B=8, C=32, H=512, W=512) fp32
//   -> out (B, 4C, H/2, W/2), out channel = 4*c + {A,H,V,D}
//
// Memory-bound streaming: 268 MB in + 268 MB out, zero reuse.
// R6 change (vs R5): make STORES 16B/lane dense too. After computing
// per-lane f32x2 results per plane/segment, a lane-pair butterfly
// (__shfl_xor 1) lets even lanes assemble the seg0 f32x4 and odd lanes
// the seg1 f32x4 of each plane. Each plane store is then ONE
// global_store_dwordx4 whose 64 lanes cover the full 1KB output row
// densely — structurally identical to the 6.29 TB/s float4-copy bench
// on both loads and stores.
//
//   load : lane l reads 16B at cols 4l and 256+4l of rows 2i, 2i+1
//   store: even lane 2k writes plane cols 4k..4k+3 (seg0),
//          odd  lane 2k+1 writes plane cols 128+4k..128+4k+3 (seg1)

typedef float f32x4 __attribute__((ext_vector_type(4)));
typedef float f32x2 __attribute__((ext_vector_type(2)));

__global__ __launch_bounds__(256) void dwt_haar_kernel(
    const float* __restrict__ x, float* __restrict__ out) {
    constexpr int H = 512, W = 512;
    constexpr int h = H / 2, w = W / 2;     // 256, 256
    constexpr int BC = 8 * 32;              // 256
    constexpr unsigned total = (unsigned)BC * h * 64;  // 4,194,304

    const unsigned stride = gridDim.x * blockDim.x;
    for (unsigned idx = blockIdx.x * blockDim.x + threadIdx.x;
         idx < total; idx += stride) {
        const unsigned l   = idx & 63;          // lane within row-pair
        const unsigned wid = idx >> 6;
        const unsigned i   = wid & (h - 1);     // 0..255
        const unsigned bc  = wid >> 8;          // 0..255

        const unsigned in_base = (bc * H + 2 * i) * W;  // < 2^26
        const f32x4 t0 = __builtin_nontemporal_load(
            reinterpret_cast<const f32x4*>(&x[in_base + 4 * l]));
        const f32x4 t1 = __builtin_nontemporal_load(
            reinterpret_cast<const f32x4*>(&x[in_base + 256 + 4 * l]));
        const f32x4 b0 = __builtin_nontemporal_load(
            reinterpret_cast<const f32x4*>(&x[in_base + W + 4 * l]));
        const f32x4 b1 = __builtin_nontemporal_load(
            reinterpret_cast<const f32x4*>(&x[in_base + W + 256 + 4 * l]));

        // seg0: output cols 2l, 2l+1 ; seg1: output cols 128+2l, 128+2l+1
        f32x2 A0, H0, V0, D0, A1, H1, V1, D1;
        {
            const float s0 = t0.x + t0.y, s1 = b0.x + b0.y;
            const float d0 = t0.x - t0.y, d1 = b0.x - b0.y;
            A0.x = (s0 + s1) * 0.5f;  H0.x = (s0 - s1) * 0.5f;
            V0.x = (d0 + d1) * 0.5f;  D0.x = (d0 - d1) * 0.5f;
        }
        {
            const float s0 = t0.z + t0.w, s1 = b0.z + b0.w;
            const float d0 = t0.z - t0.w, d1 = b0.z - b0.w;
            A0.y = (s0 + s1) * 0.5f;  H0.y = (s0 - s1) * 0.5f;
            V0.y = (d0 + d1) * 0.5f;  D0.y = (d0 - d1) * 0.5f;
        }
        {
            const float s0 = t1.x + t1.y, s1 = b1.x + b1.y;
            const float d0 = t1.x - t1.y, d1 = b1.x - b1.y;
            A1.x = (s0 + s1) * 0.5f;  H1.x = (s0 - s1) * 0.5f;
            V1.x = (d0 + d1) * 0.5f;  D1.x = (d0 - d1) * 0.5f;
        }
        {
            const float s0 = t1.z + t1.w, s1 = b1.z + b1.w;
            const float d0 = t1.z - t1.w, d1 = b1.z - b1.w;
            A1.y = (s0 + s1) * 0.5f;  H1.y = (s0 - s1) * 0.5f;
            V1.y = (d0 + d1) * 0.5f;  D1.y = (d0 - d1) * 0.5f;
        }

        // Butterfly: even lane needs partner's X0 (to finish its seg0 quad);
        // odd lane needs partner's X1 (to finish its seg1 quad). So each
        // lane SENDS X1 if even, X0 if odd.
        const bool odd = (l & 1u) != 0u;
        f32x2 rA, rH, rV, rD;
        rA.x = __shfl_xor(odd ? A0.x : A1.x, 1, 64);
        rA.y = __shfl_xor(odd ? A0.y : A1.y, 1, 64);
        rH.x = __shfl_xor(odd ? H0.x : H1.x, 1, 64);
        rH.y = __shfl_xor(odd ? H0.y : H1.y, 1, 64);
        rV.x = __shfl_xor(odd ? V0.x : V1.x, 1, 64);
        rV.y = __shfl_xor(odd ? V0.y : V1.y, 1, 64);
        rD.x = __shfl_xor(odd ? D0.x : D1.x, 1, 64);
        rD.y = __shfl_xor(odd ? D0.y : D1.y, 1, 64);

        // even: quad = (X0, rX) at col 4*(l>>1); odd: quad = (rX, X1) at
        // col 128 + 4*(l>>1). One dwordx4 store per plane covers the full
        // 1KB output row across the wave.
        const f32x4 qA = odd ? f32x4{rA.x, rA.y, A1.x, A1.y}
                             : f32x4{A0.x, A0.y, rA.x, rA.y};
        const f32x4 qH = odd ? f32x4{rH.x, rH.y, H1.x, H1.y}
                             : f32x4{H0.x, H0.y, rH.x, rH.y};
        const f32x4 qV = odd ? f32x4{rV.x, rV.y, V1.x, V1.y}
                             : f32x4{V0.x, V0.y, rV.x, rV.y};
        const f32x4 qD = odd ? f32x4{rD.x, rD.y, D1.x, D1.y}
                             : f32x4{D0.x, D0.y, rD.x, rD.y};

        constexpr unsigned plane = (unsigned)h * w;          // 65536
        const unsigned col = ((l & 1u) << 7) | ((l >> 1) << 2);
        const unsigned obase = (4 * bc * h + i) * w + col;   // < 2^26
        __builtin_nontemporal_store(qA,
            reinterpret_cast<f32x4*>(&out[obase]));
        __builtin_nontemporal_store(qH,
            reinterpret_cast<f32x4*>(&out[obase + plane]));
        __builtin_nontemporal_store(qV,
            reinterpret_cast<f32x4*>(&out[obase + 2 * plane]));
        __builtin_nontemporal_store(qD,
            reinterpret_cast<f32x4*>(&out[obase + 3 * plane]));
    }
}

extern "C" void kernel_launch(void* const* d_in, const int* in_sizes, int n_in,
                              void* d_out, int out_size, void* d_ws, size_t ws_size,
                              hipStream_t stream) {
    const float* x = (const float*)d_in[0];
    float* out = (float*)d_out;

    // total threads needed: 4,194,304; 2048 blocks x 256 -> 8 grid-stride iters.
    const int block = 256;
    const int grid = 2048;
    dwt_haar_kernel<<<grid, block, 0, stream>>>(x, out);
}